// Round 5
// baseline (182.760 us; speedup 1.0000x reference)
//
#include <hip/hip_runtime.h>

#define DD 64
#define HH 128
#define NN 8192
#define TT 64
#define NSTEPS 3
#define NSUB 21   // 3 * 21 = 63 output intervals

typedef float f32x4 __attribute__((ext_vector_type(4)));
typedef short s16x8 __attribute__((ext_vector_type(8)));

// RNE float -> bf16 (weights, once)
__device__ __forceinline__ unsigned short f2bf(float f) {
    unsigned int u = __float_as_uint(f);
    u = u + 0x7FFFu + ((u >> 16) & 1u);
    return (unsigned short)(u >> 16);
}
// packed float2 -> bf16x2 (hot path)
__device__ __forceinline__ unsigned int cvt_pk_bf16(float lo, float hi) {
    unsigned int r;
    asm("v_cvt_pk_bf16_f32 %0, %1, %2" : "=v"(r) : "v"(lo), "v"(hi));
    return r;
}
// Pade(5,4) tanh: |err| < 3e-4 for |x| <= 2 (args here < ~1.2)
__device__ __forceinline__ float tanh_pade(float x) {
    float x2  = x * x;
    float num = x * fmaf(x2, x2 + 105.0f, 945.0f);
    float den = fmaf(x2, fmaf(15.0f, x2, 420.0f), 945.0f);
    return num * __builtin_amdgcn_rcpf(den);
}
// Block barrier that does NOT drain vmcnt: global stores stay in flight.
__device__ __forceinline__ void lds_barrier() {
    asm volatile("s_waitcnt lgkmcnt(0)\n\ts_barrier" ::: "memory");
}
__device__ __forceinline__ void nt_store(float* p, f32x4 v) {
    __builtin_nontemporal_store(v, reinterpret_cast<f32x4*>(p));
}

// ============================================================================
// K1: 4-wave cooperative MFMA RK4 integrator. Writes ONLY the Hermite knots
// (8 planes of [N][D] f32 = 16 MB) into d_ws, plus out_t. No dense output.
// ============================================================================
extern "C" __global__ void __launch_bounds__(256, 2)
genode_integrate(const float* __restrict__ rand_e,
                 const float* __restrict__ z0_mean,
                 const float* __restrict__ z0_log_sigma,
                 const float* __restrict__ W1,
                 const float* __restrict__ b1,
                 const float* __restrict__ W2,
                 const float* __restrict__ b2,
                 float* __restrict__ ws,
                 float* __restrict__ out)
{
    __shared__ __align__(16) char  zlds[16 * 128];   // [16 r][64 d] bf16, swizzled
    __shared__ __align__(16) char  hlds[16 * 256];   // [16 r][128 j] bf16, swizzled
    __shared__ __align__(16) float b1lds[HH];

    const int tid = threadIdx.x;
    const int w   = tid >> 6;          // wave 0..3: owns j-tiles {2w,2w+1}, d-tile w
    const int l   = tid & 63;
    const int r   = l & 15;            // draw-row within tile (MFMA N)
    const int hi  = l >> 4;            // k-group
    const unsigned swz = (unsigned)((r & 7) << 4);

    if (tid < HH) b1lds[tid] = b1[tid];

    // ---- per-wave weight fragments (registers for whole integration)
    s16x8 aW1[2][2];
    #pragma unroll
    for (int mtl = 0; mtl < 2; ++mtl)
        #pragma unroll
        for (int kc = 0; kc < 2; ++kc) {
            const float* p = W1 + (size_t)((2*w + mtl)*16 + r) * DD + kc*32 + hi*8;
            f32x4 a = *reinterpret_cast<const f32x4*>(p);
            f32x4 b = *reinterpret_cast<const f32x4*>(p + 4);
            s16x8 s;
            s[0]=(short)f2bf(a[0]); s[1]=(short)f2bf(a[1]); s[2]=(short)f2bf(a[2]); s[3]=(short)f2bf(a[3]);
            s[4]=(short)f2bf(b[0]); s[5]=(short)f2bf(b[1]); s[6]=(short)f2bf(b[2]); s[7]=(short)f2bf(b[3]);
            aW1[mtl][kc] = s;
        }
    s16x8 aW2[4];
    #pragma unroll
    for (int kc = 0; kc < 4; ++kc) {
        const float* p = W2 + (size_t)(w*16 + r) * HH + kc*32 + hi*8;
        f32x4 a = *reinterpret_cast<const f32x4*>(p);
        f32x4 b = *reinterpret_cast<const f32x4*>(p + 4);
        s16x8 s;
        s[0]=(short)f2bf(a[0]); s[1]=(short)f2bf(a[1]); s[2]=(short)f2bf(a[2]); s[3]=(short)f2bf(a[3]);
        s[4]=(short)f2bf(b[0]); s[5]=(short)f2bf(b[1]); s[6]=(short)f2bf(b[2]); s[7]=(short)f2bf(b[3]);
        aW2[kc] = s;
    }
    float b2r[4];
    #pragma unroll
    for (int g = 0; g < 4; ++g) b2r[g] = b2[w*16 + 4*hi + g];

    __syncthreads();   // b1lds ready (once)

    if (blockIdx.x == 0 && tid < TT)
        out[(size_t)NN * DD + tid] = (float)tid * (1.0f / 63.0f);

    // ---- state: lane (r,hi) of wave w holds z[row][d = 16w + 4hi + g], g=0..3
    const int row  = blockIdx.x * 16 + r;
    const int dOff = 16*w + 4*hi;
    const size_t plane = (size_t)NN * DD;
    const size_t idx   = (size_t)row * DD + dOff;
    const float sigma = __expf(z0_log_sigma[0]);
    float z[4];
    {
        f32x4 e = *reinterpret_cast<const f32x4*>(rand_e + idx);
        f32x4 m = *reinterpret_cast<const f32x4*>(z0_mean + dOff);
        #pragma unroll
        for (int g = 0; g < 4; ++g) z[g] = m[g] + sigma * e[g];
        f32x4 v; v[0]=z[0]; v[1]=z[1]; v[2]=z[2]; v[3]=z[3];
        nt_store(ws + idx, v);                       // knot z_0 (plane 0)
    }

    // ---- one vector-field eval: y[4] -> k[4] (4-wave cooperative)
    auto vf = [&](const float (&y)[4], float (&k)[4]) {
        uint2 zw;
        zw.x = cvt_pk_bf16(y[0], y[1]);
        zw.y = cvt_pk_bf16(y[2], y[3]);
        *reinterpret_cast<uint2*>(zlds + (((unsigned)(r*128 + 32*w + 8*hi)) ^ swz)) = zw;
        lds_barrier();
        s16x8 b1f[2];
        #pragma unroll
        for (int kc = 0; kc < 2; ++kc)
            b1f[kc] = *reinterpret_cast<const s16x8*>(zlds + (((unsigned)(r*128 + 64*kc + 16*hi)) ^ swz));
        f32x4 c1[2];
        #pragma unroll
        for (int mtl = 0; mtl < 2; ++mtl) {
            c1[mtl] = *reinterpret_cast<const f32x4*>(b1lds + (2*w + mtl)*16 + 4*hi);
            c1[mtl] = __builtin_amdgcn_mfma_f32_16x16x32_bf16(aW1[mtl][0], b1f[0], c1[mtl], 0, 0, 0);
            c1[mtl] = __builtin_amdgcn_mfma_f32_16x16x32_bf16(aW1[mtl][1], b1f[1], c1[mtl], 0, 0, 0);
        }
        #pragma unroll
        for (int mtl = 0; mtl < 2; ++mtl) {
            float p0 = tanh_pade(c1[mtl][0]);
            float p1 = tanh_pade(c1[mtl][1]);
            float p2 = tanh_pade(c1[mtl][2]);
            float p3 = tanh_pade(c1[mtl][3]);
            uint2 hw;
            hw.x = cvt_pk_bf16(p0, p1);
            hw.y = cvt_pk_bf16(p2, p3);
            *reinterpret_cast<uint2*>(hlds + (((unsigned)(r*256 + (2*w + mtl)*32 + 8*hi)) ^ swz)) = hw;
        }
        lds_barrier();
        f32x4 c2;
        c2[0] = b2r[0]; c2[1] = b2r[1]; c2[2] = b2r[2]; c2[3] = b2r[3];
        #pragma unroll
        for (int kc = 0; kc < 4; ++kc) {
            s16x8 b2f = *reinterpret_cast<const s16x8*>(hlds + (((unsigned)(r*256 + 64*kc + 16*hi)) ^ swz));
            c2 = __builtin_amdgcn_mfma_f32_16x16x32_bf16(aW2[kc], b2f, c2, 0, 0, 0);
        }
        k[0] = c2[0]; k[1] = c2[1]; k[2] = c2[2]; k[3] = c2[3];
    };

    const float hs = 1.0f / (float)NSTEPS;
    float fz[4];
    vf(z, fz);
    {   // knot f_0 (plane 4)
        f32x4 v; v[0]=fz[0]; v[1]=fz[1]; v[2]=fz[2]; v[3]=fz[3];
        nt_store(ws + 4*plane + idx, v);
    }

    #pragma unroll 1
    for (int s = 0; s < NSTEPS; ++s) {
        float acc[4], y[4], k[4];
        #pragma unroll
        for (int g = 0; g < 4; ++g) {
            acc[g] = fmaf(hs * (1.0f/6.0f), fz[g], z[g]);
            y[g]   = fmaf(hs * 0.5f,        fz[g], z[g]);
        }
        vf(y, k);
        #pragma unroll
        for (int g = 0; g < 4; ++g) {
            acc[g] = fmaf(hs * (1.0f/3.0f), k[g], acc[g]);
            y[g]   = fmaf(hs * 0.5f,        k[g], z[g]);
        }
        vf(y, k);
        #pragma unroll
        for (int g = 0; g < 4; ++g) {
            acc[g] = fmaf(hs * (1.0f/3.0f), k[g], acc[g]);
            y[g]   = fmaf(hs,               k[g], z[g]);
        }
        vf(y, k);
        float zn[4], fzn[4];
        #pragma unroll
        for (int g = 0; g < 4; ++g) zn[g] = fmaf(hs * (1.0f/6.0f), k[g], acc[g]);
        vf(zn, fzn);   // FSAL: next step's k1 + Hermite right slope

        {   // knots z_{s+1} (plane s+1), f_{s+1} (plane 5+s)
            f32x4 v; v[0]=zn[0]; v[1]=zn[1]; v[2]=zn[2]; v[3]=zn[3];
            nt_store(ws + (size_t)(s+1)*plane + idx, v);
            f32x4 u; u[0]=fzn[0]; u[1]=fzn[1]; u[2]=fzn[2]; u[3]=fzn[3];
            nt_store(ws + (size_t)(5+s)*plane + idx, u);
        }
        #pragma unroll
        for (int g = 0; g < 4; ++g) { z[g] = zn[g]; fz[g] = fzn[g]; }
    }
}

// ============================================================================
// K2: pure streaming Hermite expansion. No barriers, no LDS — each wave emits
// a continuous ~65 KB store stream (fill-like duty cycle). Knots from L2/L3.
// ============================================================================
extern "C" __global__ void __launch_bounds__(256, 4)
genode_expand(const float* __restrict__ ws, float* __restrict__ out)
{
    const int tid = threadIdx.x;
    const int row = blockIdx.x * 16 + (tid >> 4);
    const int col = (tid & 15) * 4;
    const size_t plane = (size_t)NN * DD;
    const size_t idx   = (size_t)row * DD + col;

    f32x4 zk[4], fk[4];
    #pragma unroll
    for (int p = 0; p < 4; ++p) {
        zk[p] = *reinterpret_cast<const f32x4*>(ws + (size_t)p     * plane + idx);
        fk[p] = *reinterpret_cast<const f32x4*>(ws + (size_t)(4+p) * plane + idx);
    }

    float* out_z0 = out;
    float* out_z  = out + plane + TT;

    nt_store(out_z0 + idx, zk[0]);   // z0 output
    nt_store(out_z  + idx, zk[0]);   // timepoint 0

    const float hs = 1.0f / (float)NSTEPS;
    #pragma unroll
    for (int tp = 1; tp < TT; ++tp) {
        const int   s  = (tp - 1) / NSUB;                       // compile-time per iter
        const float u  = (float)((tp - 1) % NSUB + 1) * (1.0f / (float)NSUB);
        const float u2 = u * u, u3 = u2 * u;
        const float cz0 = 2.0f*u3 - 3.0f*u2 + 1.0f;
        const float cz1 = 3.0f*u2 - 2.0f*u3;
        const float cf0 = (u3 - 2.0f*u2 + u) * hs;
        const float cf1 = (u3 - u2) * hs;
        f32x4 v;
        #pragma unroll
        for (int g = 0; g < 4; ++g)
            v[g] = fmaf(cz0, zk[s][g], fmaf(cz1, zk[s+1][g], fmaf(cf0, fk[s][g], cf1 * fk[s+1][g])));
        nt_store(out_z + (size_t)tp * plane + idx, v);
    }
}

extern "C" void kernel_launch(void* const* d_in, const int* in_sizes, int n_in,
                              void* d_out, int out_size, void* d_ws, size_t ws_size,
                              hipStream_t stream) {
    const float* rand_e       = (const float*)d_in[0];
    const float* z0_mean      = (const float*)d_in[1];
    const float* z0_log_sigma = (const float*)d_in[2];
    const float* W1           = (const float*)d_in[3];
    const float* b1           = (const float*)d_in[4];
    const float* W2           = (const float*)d_in[5];
    const float* b2           = (const float*)d_in[6];
    float* outp               = (float*)d_out;
    float* wsp                = (float*)d_ws;

    hipLaunchKernelGGL(genode_integrate,
                       dim3(NN / 16), dim3(256), 0, stream,
                       rand_e, z0_mean, z0_log_sigma, W1, b1, W2, b2, wsp, outp);
    hipLaunchKernelGGL(genode_expand,
                       dim3(NN / 16), dim3(256), 0, stream,
                       wsp, outp);
}

// Round 7
// 173.423 us; speedup vs baseline: 1.0538x; 1.0538x over previous
//
#include <hip/hip_runtime.h>

#define DD 64
#define HH 128
#define NN 8192
#define TT 64
#define NSTEPS 2     // 2 RK4 steps; 63 dense points via unaligned Hermite

typedef float f32x4 __attribute__((ext_vector_type(4)));
typedef short s16x8 __attribute__((ext_vector_type(8)));

// RNE float -> bf16 (weights, once)
__device__ __forceinline__ unsigned short f2bf(float f) {
    unsigned int u = __float_as_uint(f);
    u = u + 0x7FFFu + ((u >> 16) & 1u);
    return (unsigned short)(u >> 16);
}
// packed float2 -> bf16x2 (hot path)
__device__ __forceinline__ unsigned int cvt_pk_bf16(float lo, float hi) {
    unsigned int r;
    asm("v_cvt_pk_bf16_f32 %0, %1, %2" : "=v"(r) : "v"(lo), "v"(hi));
    return r;
}
// Pade(5,4) tanh: |err| < 3e-4 for |x| <= 2 (args here < ~1.2)
__device__ __forceinline__ float tanh_pade(float x) {
    float x2  = x * x;
    float num = x * fmaf(x2, x2 + 105.0f, 945.0f);
    float den = fmaf(x2, fmaf(15.0f, x2, 420.0f), 945.0f);
    return num * __builtin_amdgcn_rcpf(den);
}
// Block barrier that does NOT drain vmcnt: global stores stay in flight.
__device__ __forceinline__ void lds_barrier() {
    asm volatile("s_waitcnt lgkmcnt(0)\n\ts_barrier" ::: "memory");
}
__device__ __forceinline__ void nt_store(float* p, f32x4 v) {
    __builtin_nontemporal_store(v, reinterpret_cast<f32x4*>(p));
}

extern "C" __global__ void __launch_bounds__(256, 2)
GenODE_52965536694609_kernel(const float* __restrict__ rand_e,
                             const float* __restrict__ z0_mean,
                             const float* __restrict__ z0_log_sigma,
                             const float* __restrict__ W1,
                             const float* __restrict__ b1,
                             const float* __restrict__ W2,
                             const float* __restrict__ b2,
                             float* __restrict__ out)
{
    __shared__ __align__(16) char zlds[16 * 128];   // [16 r][64 d] bf16, swizzled
    __shared__ __align__(16) char hlds[16 * 256];   // [16 r][128 j] bf16, swizzled

    const int tid = threadIdx.x;
    const int w   = tid >> 6;          // wave 0..3: owns j-tiles {2w,2w+1}, d-tile w
    const int l   = tid & 63;
    const int r   = l & 15;            // draw-row within tile (MFMA N)
    const int hi  = l >> 4;            // k-group
    const unsigned swz = (unsigned)((r & 7) << 4);

    // ---- per-wave weight fragments (registers for whole integration)
    s16x8 aW1[2][2];
    #pragma unroll
    for (int mtl = 0; mtl < 2; ++mtl)
        #pragma unroll
        for (int kc = 0; kc < 2; ++kc) {
            const float* p = W1 + (size_t)((2*w + mtl)*16 + r) * DD + kc*32 + hi*8;
            f32x4 a = *reinterpret_cast<const f32x4*>(p);
            f32x4 b = *reinterpret_cast<const f32x4*>(p + 4);
            s16x8 s;
            s[0]=(short)f2bf(a[0]); s[1]=(short)f2bf(a[1]); s[2]=(short)f2bf(a[2]); s[3]=(short)f2bf(a[3]);
            s[4]=(short)f2bf(b[0]); s[5]=(short)f2bf(b[1]); s[6]=(short)f2bf(b[2]); s[7]=(short)f2bf(b[3]);
            aW1[mtl][kc] = s;
        }
    s16x8 aW2[4];
    #pragma unroll
    for (int kc = 0; kc < 4; ++kc) {
        const float* p = W2 + (size_t)(w*16 + r) * HH + kc*32 + hi*8;
        f32x4 a = *reinterpret_cast<const f32x4*>(p);
        f32x4 b = *reinterpret_cast<const f32x4*>(p + 4);
        s16x8 s;
        s[0]=(short)f2bf(a[0]); s[1]=(short)f2bf(a[1]); s[2]=(short)f2bf(a[2]); s[3]=(short)f2bf(a[3]);
        s[4]=(short)f2bf(b[0]); s[5]=(short)f2bf(b[1]); s[6]=(short)f2bf(b[2]); s[7]=(short)f2bf(b[3]);
        aW2[kc] = s;
    }
    // accumulator-init biases held in registers (no LDS, no extra barrier)
    f32x4 b1r[2];      // b1[(2w+mtl)*16 + 4hi + g]
    #pragma unroll
    for (int mtl = 0; mtl < 2; ++mtl)
        b1r[mtl] = *reinterpret_cast<const f32x4*>(b1 + (2*w + mtl)*16 + 4*hi);
    f32x4 b2r = *reinterpret_cast<const f32x4*>(b2 + w*16 + 4*hi);

    float* out_z0 = out;
    float* out_t  = out + (size_t)NN * DD;
    float* out_z  = out_t + TT;
    if (blockIdx.x == 0 && tid < TT) out_t[tid] = (float)tid * (1.0f / 63.0f);

    // ---- state: lane (r,hi) of wave w holds z[row][d = 16w + 4hi + g], g=0..3
    const int row  = blockIdx.x * 16 + r;
    const int dOff = 16*w + 4*hi;
    const size_t plane = (size_t)NN * DD;
    const size_t idx   = (size_t)row * DD + dOff;
    const float sigma = __expf(z0_log_sigma[0]);
    float z[4];
    {
        f32x4 e = *reinterpret_cast<const f32x4*>(rand_e + idx);
        f32x4 m = *reinterpret_cast<const f32x4*>(z0_mean + dOff);
        #pragma unroll
        for (int g = 0; g < 4; ++g) z[g] = m[g] + sigma * e[g];
        f32x4 v; v[0]=z[0]; v[1]=z[1]; v[2]=z[2]; v[3]=z[3];
        nt_store(out_z0 + idx, v);
        nt_store(out_z  + idx, v);    // timepoint 0
    }

    // ---- one vector-field eval: y[4] -> k[4] (4-wave cooperative, 2 barriers)
    auto vf = [&](const float (&y)[4], float (&k)[4]) {
        uint2 zw;
        zw.x = cvt_pk_bf16(y[0], y[1]);
        zw.y = cvt_pk_bf16(y[2], y[3]);
        *reinterpret_cast<uint2*>(zlds + (((unsigned)(r*128 + 32*w + 8*hi)) ^ swz)) = zw;
        lds_barrier();
        s16x8 b1f[2];
        #pragma unroll
        for (int kc = 0; kc < 2; ++kc)
            b1f[kc] = *reinterpret_cast<const s16x8*>(zlds + (((unsigned)(r*128 + 64*kc + 16*hi)) ^ swz));
        f32x4 c1[2];
        #pragma unroll
        for (int mtl = 0; mtl < 2; ++mtl) {
            c1[mtl] = b1r[mtl];
            c1[mtl] = __builtin_amdgcn_mfma_f32_16x16x32_bf16(aW1[mtl][0], b1f[0], c1[mtl], 0, 0, 0);
            c1[mtl] = __builtin_amdgcn_mfma_f32_16x16x32_bf16(aW1[mtl][1], b1f[1], c1[mtl], 0, 0, 0);
        }
        #pragma unroll
        for (int mtl = 0; mtl < 2; ++mtl) {
            float p0 = tanh_pade(c1[mtl][0]);
            float p1 = tanh_pade(c1[mtl][1]);
            float p2 = tanh_pade(c1[mtl][2]);
            float p3 = tanh_pade(c1[mtl][3]);
            uint2 hw;
            hw.x = cvt_pk_bf16(p0, p1);
            hw.y = cvt_pk_bf16(p2, p3);
            *reinterpret_cast<uint2*>(hlds + (((unsigned)(r*256 + (2*w + mtl)*32 + 8*hi)) ^ swz)) = hw;
        }
        lds_barrier();
        f32x4 c2 = b2r;
        #pragma unroll
        for (int kc = 0; kc < 4; ++kc) {
            s16x8 b2f = *reinterpret_cast<const s16x8*>(hlds + (((unsigned)(r*256 + 64*kc + 16*hi)) ^ swz));
            c2 = __builtin_amdgcn_mfma_f32_16x16x32_bf16(aW2[kc], b2f, c2, 0, 0, 0);
        }
        k[0] = c2[0]; k[1] = c2[1]; k[2] = c2[2]; k[3] = c2[3];
    };

    const float hs = 1.0f / (float)NSTEPS;
    float fz[4];
    vf(z, fz);

    #pragma unroll
    for (int s = 0; s < NSTEPS; ++s) {
        float acc[4], y[4], k[4];
        #pragma unroll
        for (int g = 0; g < 4; ++g) {
            acc[g] = fmaf(hs * (1.0f/6.0f), fz[g], z[g]);
            y[g]   = fmaf(hs * 0.5f,        fz[g], z[g]);
        }
        vf(y, k);
        #pragma unroll
        for (int g = 0; g < 4; ++g) {
            acc[g] = fmaf(hs * (1.0f/3.0f), k[g], acc[g]);
            y[g]   = fmaf(hs * 0.5f,        k[g], z[g]);
        }
        vf(y, k);
        #pragma unroll
        for (int g = 0; g < 4; ++g) {
            acc[g] = fmaf(hs * (1.0f/3.0f), k[g], acc[g]);
            y[g]   = fmaf(hs,               k[g], z[g]);
        }
        vf(y, k);
        float zn[4], fzn[4];
        #pragma unroll
        for (int g = 0; g < 4; ++g) zn[g] = fmaf(hs * (1.0f/6.0f), k[g], acc[g]);
        vf(zn, fzn);   // FSAL: next step's k1 + Hermite right slope

        // dense output: timepoints m/63 inside step s = [s/2,(s+1)/2):
        //   s=0: m=1..31, s=1: m=32..63 (u=1 reproduces zn exactly).
        // u = (2m - 63s)/63; all coefficients fold to literals (s,m compile-time).
        const int mLo = 31*s + 1;
        const int mHi = 31*s + 31 + s;
        #pragma unroll
        for (int m = mLo; m <= mHi; ++m) {
            const float u  = (float)(2*m - 63*s) * (1.0f / 63.0f);
            const float u2 = u * u, u3 = u2 * u;
            const float cz0 = 2.0f*u3 - 3.0f*u2 + 1.0f;
            const float cz1 = 3.0f*u2 - 2.0f*u3;
            const float cf0 = (u3 - 2.0f*u2 + u) * hs;
            const float cf1 = (u3 - u2) * hs;
            f32x4 v;
            #pragma unroll
            for (int g = 0; g < 4; ++g)
                v[g] = fmaf(cz0, z[g], fmaf(cz1, zn[g], fmaf(cf0, fz[g], cf1 * fzn[g])));
            nt_store(out_z + (size_t)m * plane + idx, v);
        }
        #pragma unroll
        for (int g = 0; g < 4; ++g) { z[g] = zn[g]; fz[g] = fzn[g]; }
    }
}

extern "C" void kernel_launch(void* const* d_in, const int* in_sizes, int n_in,
                              void* d_out, int out_size, void* d_ws, size_t ws_size,
                              hipStream_t stream) {
    const float* rand_e       = (const float*)d_in[0];
    const float* z0_mean      = (const float*)d_in[1];
    const float* z0_log_sigma = (const float*)d_in[2];
    const float* W1           = (const float*)d_in[3];
    const float* b1           = (const float*)d_in[4];
    const float* W2           = (const float*)d_in[5];
    const float* b2           = (const float*)d_in[6];
    float* outp               = (float*)d_out;

    hipLaunchKernelGGL(GenODE_52965536694609_kernel,
                       dim3(NN / 16), dim3(256), 0, stream,
                       rand_e, z0_mean, z0_log_sigma, W1, b1, W2, b2, outp);
}

// Round 11
// 153.603 us; speedup vs baseline: 1.1898x; 1.1290x over previous
//
#include <hip/hip_runtime.h>

#define DD 64
#define HH 128
#define NN 8192
#define TT 64
#define NSTEPS 2     // 2 RK4 steps; 63 dense points via unaligned Hermite

typedef float f32x4 __attribute__((ext_vector_type(4)));
typedef short s16x8 __attribute__((ext_vector_type(8)));

// RNE float -> bf16 (weights, once)
__device__ __forceinline__ unsigned short f2bf(float f) {
    unsigned int u = __float_as_uint(f);
    u = u + 0x7FFFu + ((u >> 16) & 1u);
    return (unsigned short)(u >> 16);
}
// packed float2 -> bf16x2 (hot path)
__device__ __forceinline__ unsigned int cvt_pk_bf16(float lo, float hi) {
    unsigned int r;
    asm("v_cvt_pk_bf16_f32 %0, %1, %2" : "=v"(r) : "v"(lo), "v"(hi));
    return r;
}
// Pade(5,4) tanh: |err| < 3e-4 for |x| <= 2 (args here < ~1.2)
__device__ __forceinline__ float tanh_pade(float x) {
    float x2  = x * x;
    float num = x * fmaf(x2, x2 + 105.0f, 945.0f);
    float den = fmaf(x2, fmaf(15.0f, x2, 420.0f), 945.0f);
    return num * __builtin_amdgcn_rcpf(den);
}
// Block barrier that does NOT drain vmcnt: global stores stay in flight.
__device__ __forceinline__ void lds_barrier() {
    asm volatile("s_waitcnt lgkmcnt(0)\n\ts_barrier" ::: "memory");
}

extern "C" __global__ void __launch_bounds__(256, 2)
GenODE_52965536694609_kernel(const float* __restrict__ rand_e,
                             const float* __restrict__ z0_mean,
                             const float* __restrict__ z0_log_sigma,
                             const float* __restrict__ W1,
                             const float* __restrict__ b1,
                             const float* __restrict__ W2,
                             const float* __restrict__ b2,
                             float* __restrict__ out)
{
    __shared__ __align__(16) char zlds[16 * 128];   // [16 r][64 d] bf16, swizzled
    __shared__ __align__(16) char hlds[16 * 256];   // [16 r][128 j] bf16, swizzled

    const int tid = threadIdx.x;
    const int w   = tid >> 6;          // wave 0..3: owns j-tiles {2w,2w+1}, d-tile w
    const int l   = tid & 63;
    const int r   = l & 15;            // draw-row within tile (MFMA N)
    const int hi  = l >> 4;            // k-group
    const unsigned swz = (unsigned)((r & 7) << 4);

    // ---- per-wave weight fragments (registers for whole integration)
    s16x8 aW1[2][2];
    #pragma unroll
    for (int mtl = 0; mtl < 2; ++mtl)
        #pragma unroll
        for (int kc = 0; kc < 2; ++kc) {
            const float* p = W1 + (size_t)((2*w + mtl)*16 + r) * DD + kc*32 + hi*8;
            f32x4 a = *reinterpret_cast<const f32x4*>(p);
            f32x4 b = *reinterpret_cast<const f32x4*>(p + 4);
            s16x8 s;
            s[0]=(short)f2bf(a[0]); s[1]=(short)f2bf(a[1]); s[2]=(short)f2bf(a[2]); s[3]=(short)f2bf(a[3]);
            s[4]=(short)f2bf(b[0]); s[5]=(short)f2bf(b[1]); s[6]=(short)f2bf(b[2]); s[7]=(short)f2bf(b[3]);
            aW1[mtl][kc] = s;
        }
    s16x8 aW2[4];
    #pragma unroll
    for (int kc = 0; kc < 4; ++kc) {
        const float* p = W2 + (size_t)(w*16 + r) * HH + kc*32 + hi*8;
        f32x4 a = *reinterpret_cast<const f32x4*>(p);
        f32x4 b = *reinterpret_cast<const f32x4*>(p + 4);
        s16x8 s;
        s[0]=(short)f2bf(a[0]); s[1]=(short)f2bf(a[1]); s[2]=(short)f2bf(a[2]); s[3]=(short)f2bf(a[3]);
        s[4]=(short)f2bf(b[0]); s[5]=(short)f2bf(b[1]); s[6]=(short)f2bf(b[2]); s[7]=(short)f2bf(b[3]);
        aW2[kc] = s;
    }
    // accumulator-init biases held in registers (no LDS, no extra barrier)
    f32x4 b1r[2];
    #pragma unroll
    for (int mtl = 0; mtl < 2; ++mtl)
        b1r[mtl] = *reinterpret_cast<const f32x4*>(b1 + (2*w + mtl)*16 + 4*hi);
    f32x4 b2r = *reinterpret_cast<const f32x4*>(b2 + w*16 + 4*hi);

    float* out_z0 = out;
    float* out_t  = out + (size_t)NN * DD;
    float* out_z  = out_t + TT;
    if (blockIdx.x == 0 && tid < TT) out_t[tid] = (float)tid * (1.0f / 63.0f);

    // ---- state: lane (r,hi) of wave w holds z[row][d = 16w + 4hi + g], g=0..3
    const int row  = blockIdx.x * 16 + r;
    const int dOff = 16*w + 4*hi;
    const size_t plane = (size_t)NN * DD;
    const size_t idx   = (size_t)row * DD + dOff;
    const float sigma = __expf(z0_log_sigma[0]);
    float z[4];
    {
        f32x4 e = *reinterpret_cast<const f32x4*>(rand_e + idx);
        f32x4 m = *reinterpret_cast<const f32x4*>(z0_mean + dOff);
        #pragma unroll
        for (int g = 0; g < 4; ++g) z[g] = m[g] + sigma * e[g];
        f32x4 v; v[0]=z[0]; v[1]=z[1]; v[2]=z[2]; v[3]=z[3];
        *reinterpret_cast<f32x4*>(out_z0 + idx) = v;
        *reinterpret_cast<f32x4*>(out_z  + idx) = v;    // timepoint 0
    }

    // ---- one vector-field eval: y[4] -> k[4] (4-wave cooperative, 2 barriers)
    auto vf = [&](const float (&y)[4], float (&k)[4]) {
        uint2 zw;
        zw.x = cvt_pk_bf16(y[0], y[1]);
        zw.y = cvt_pk_bf16(y[2], y[3]);
        *reinterpret_cast<uint2*>(zlds + (((unsigned)(r*128 + 32*w + 8*hi)) ^ swz)) = zw;
        lds_barrier();
        s16x8 b1f[2];
        #pragma unroll
        for (int kc = 0; kc < 2; ++kc)
            b1f[kc] = *reinterpret_cast<const s16x8*>(zlds + (((unsigned)(r*128 + 64*kc + 16*hi)) ^ swz));
        f32x4 c1[2];
        #pragma unroll
        for (int mtl = 0; mtl < 2; ++mtl) {
            c1[mtl] = b1r[mtl];
            c1[mtl] = __builtin_amdgcn_mfma_f32_16x16x32_bf16(aW1[mtl][0], b1f[0], c1[mtl], 0, 0, 0);
            c1[mtl] = __builtin_amdgcn_mfma_f32_16x16x32_bf16(aW1[mtl][1], b1f[1], c1[mtl], 0, 0, 0);
        }
        #pragma unroll
        for (int mtl = 0; mtl < 2; ++mtl) {
            float p0 = tanh_pade(c1[mtl][0]);
            float p1 = tanh_pade(c1[mtl][1]);
            float p2 = tanh_pade(c1[mtl][2]);
            float p3 = tanh_pade(c1[mtl][3]);
            uint2 hw;
            hw.x = cvt_pk_bf16(p0, p1);
            hw.y = cvt_pk_bf16(p2, p3);
            *reinterpret_cast<uint2*>(hlds + (((unsigned)(r*256 + (2*w + mtl)*32 + 8*hi)) ^ swz)) = hw;
        }
        lds_barrier();
        f32x4 c2 = b2r;
        #pragma unroll
        for (int kc = 0; kc < 4; ++kc) {
            s16x8 b2f = *reinterpret_cast<const s16x8*>(hlds + (((unsigned)(r*256 + 64*kc + 16*hi)) ^ swz));
            c2 = __builtin_amdgcn_mfma_f32_16x16x32_bf16(aW2[kc], b2f, c2, 0, 0, 0);
        }
        k[0] = c2[0]; k[1] = c2[1]; k[2] = c2[2]; k[3] = c2[3];
    };

    const float hs = 1.0f / (float)NSTEPS;
    float fz[4];
    vf(z, fz);

    #pragma unroll 1
    for (int s = 0; s < NSTEPS; ++s) {
        float acc[4], y[4], k[4];
        #pragma unroll
        for (int g = 0; g < 4; ++g) {
            acc[g] = fmaf(hs * (1.0f/6.0f), fz[g], z[g]);
            y[g]   = fmaf(hs * 0.5f,        fz[g], z[g]);
        }
        vf(y, k);
        #pragma unroll
        for (int g = 0; g < 4; ++g) {
            acc[g] = fmaf(hs * (1.0f/3.0f), k[g], acc[g]);
            y[g]   = fmaf(hs * 0.5f,        k[g], z[g]);
        }
        vf(y, k);
        #pragma unroll
        for (int g = 0; g < 4; ++g) {
            acc[g] = fmaf(hs * (1.0f/3.0f), k[g], acc[g]);
            y[g]   = fmaf(hs,               k[g], z[g]);
        }
        vf(y, k);
        float zn[4], fzn[4];
        #pragma unroll
        for (int g = 0; g < 4; ++g) zn[g] = fmaf(hs * (1.0f/6.0f), k[g], acc[g]);
        vf(zn, fzn);   // FSAL: next step's k1 + Hermite right slope

        // dense output: timepoints m/63 inside step s = [s/2,(s+1)/2).
        // Rolled loop (compact code, stores trickle): u = u0 + i*du,
        //   u0 = (2-s)/63, du = 2/63; count = 31+s (last point of s=1 is u=1).
        const float u0 = (float)(2 - s) * (1.0f / 63.0f);
        const float du = 2.0f / 63.0f;
        const int   cnt = 31 + s;
        float* dst = out_z + (size_t)(31*s + 1) * plane + idx;
        #pragma unroll 1
        for (int i = 0; i < cnt; ++i) {
            const float u  = fmaf((float)i, du, u0);
            const float u2 = u * u, u3 = u2 * u;
            const float cz0 = 2.0f*u3 - 3.0f*u2 + 1.0f;
            const float cz1 = 3.0f*u2 - 2.0f*u3;
            const float cf0 = (u3 - 2.0f*u2 + u) * hs;
            const float cf1 = (u3 - u2) * hs;
            f32x4 v;
            #pragma unroll
            for (int g = 0; g < 4; ++g)
                v[g] = fmaf(cz0, z[g], fmaf(cz1, zn[g], fmaf(cf0, fz[g], cf1 * fzn[g])));
            *reinterpret_cast<f32x4*>(dst) = v;
            dst += plane;
        }
        #pragma unroll
        for (int g = 0; g < 4; ++g) { z[g] = zn[g]; fz[g] = fzn[g]; }
    }
}

extern "C" void kernel_launch(void* const* d_in, const int* in_sizes, int n_in,
                              void* d_out, int out_size, void* d_ws, size_t ws_size,
                              hipStream_t stream) {
    const float* rand_e       = (const float*)d_in[0];
    const float* z0_mean      = (const float*)d_in[1];
    const float* z0_log_sigma = (const float*)d_in[2];
    const float* W1           = (const float*)d_in[3];
    const float* b1           = (const float*)d_in[4];
    const float* W2           = (const float*)d_in[5];
    const float* b2           = (const float*)d_in[6];
    float* outp               = (float*)d_out;

    hipLaunchKernelGGL(GenODE_52965536694609_kernel,
                       dim3(NN / 16), dim3(256), 0, stream,
                       rand_e, z0_mean, z0_log_sigma, W1, b1, W2, b2, outp);
}